// Round 7
// baseline (217.270 us; speedup 1.0000x reference)
//
#include <hip/hip_runtime.h>

#define BLOCK 256
#define GRID 4096
#define NXCD 8
#define UNROLL 8

typedef float f32x4 __attribute__((ext_vector_type(4)));
typedef int   i32x2 __attribute__((ext_vector_type(2)));

// Block-contiguous stride-1 layout, nontemporal loads, unroll x8,
// XCD-aware chunk assignment: consecutive chunks land on the SAME XCD
// (dispatch round-robins blockIdx across XCDs), so each XCD streams one
// contiguous 1/8 of the arrays -> better L2/L3-slice + DRAM locality.
__global__ __launch_bounds__(BLOCK) void loss_partial_kernel(
    const f32x4* __restrict__ pred4,  // N/2 elements (2 rows per float4)
    const i32x2* __restrict__ tgt2,   // N/2 elements (2 targets per int2)
    float* __restrict__ partials,     // GRID
    int npairs)                       // N/2
{
    // bijective XCD swizzle (GRID % NXCD == 0)
    const int cpx   = GRID / NXCD;
    const int chunk = (blockIdx.x & (NXCD - 1)) * cpx + (blockIdx.x >> 3);

    const int ppb  = (npairs + GRID - 1) / GRID;   // 2048 pairs per chunk
    const int base = chunk * ppb;
    const int end  = min(base + ppb, npairs);

    float acc = 0.0f;
    int k = base + threadIdx.x;

    for (; k + (UNROLL - 1) * BLOCK < end; k += UNROLL * BLOCK) {
        f32x4 p[UNROLL];
        i32x2 t[UNROLL];
#pragma unroll
        for (int u = 0; u < UNROLL; ++u) p[u] = __builtin_nontemporal_load(&pred4[k + u * BLOCK]);
#pragma unroll
        for (int u = 0; u < UNROLL; ++u) t[u] = __builtin_nontemporal_load(&tgt2[k + u * BLOCK]);
#pragma unroll
        for (int u = 0; u < UNROLL; ++u) {
            {
                bool z = (t[u][0] == 0);
                float a = z ? p[u][0] : p[u][1];
                float b = z ? p[u][1] : p[u][0];
                float d = 1.0f - a;
                acc += fmaf(d, d, b * b) + ((a < b) ? 2.0f : 0.0f);
            }
            {
                bool z = (t[u][1] == 0);
                float a = z ? p[u][2] : p[u][3];
                float b = z ? p[u][3] : p[u][2];
                float d = 1.0f - a;
                acc += fmaf(d, d, b * b) + ((a < b) ? 2.0f : 0.0f);
            }
        }
    }
    for (; k < end; k += BLOCK) {   // tail (not taken at N=16777216)
        f32x4 p = __builtin_nontemporal_load(&pred4[k]);
        i32x2 t = __builtin_nontemporal_load(&tgt2[k]);
        {
            bool z = (t[0] == 0);
            float a = z ? p[0] : p[1];
            float b = z ? p[1] : p[0];
            float d = 1.0f - a;
            acc += fmaf(d, d, b * b) + ((a < b) ? 2.0f : 0.0f);
        }
        {
            bool z = (t[1] == 0);
            float a = z ? p[2] : p[3];
            float b = z ? p[3] : p[2];
            float d = 1.0f - a;
            acc += fmaf(d, d, b * b) + ((a < b) ? 2.0f : 0.0f);
        }
    }

#pragma unroll
    for (int off = 32; off > 0; off >>= 1)
        acc += __shfl_down(acc, off, 64);

    __shared__ float wsum[BLOCK / 64];
    const int lane = threadIdx.x & 63;
    const int wid  = threadIdx.x >> 6;
    if (lane == 0) wsum[wid] = acc;
    __syncthreads();
    if (threadIdx.x == 0) {
        float s = 0.0f;
#pragma unroll
        for (int w = 0; w < BLOCK / 64; ++w) s += wsum[w];
        partials[blockIdx.x] = s;
    }
}

__global__ __launch_bounds__(BLOCK) void loss_final_kernel(
    const float* __restrict__ partials, float* __restrict__ out,
    int nparts, float inv_n)
{
    float acc = 0.0f;
    for (int i = threadIdx.x; i < nparts; i += BLOCK)
        acc += partials[i];
#pragma unroll
    for (int off = 32; off > 0; off >>= 1)
        acc += __shfl_down(acc, off, 64);

    __shared__ float wsum[BLOCK / 64];
    const int lane = threadIdx.x & 63;
    const int wid  = threadIdx.x >> 6;
    if (lane == 0) wsum[wid] = acc;
    __syncthreads();
    if (threadIdx.x == 0) {
        float s = 0.0f;
#pragma unroll
        for (int w = 0; w < BLOCK / 64; ++w) s += wsum[w];
        out[0] = s * inv_n;
    }
}

extern "C" void kernel_launch(void* const* d_in, const int* in_sizes, int n_in,
                              void* d_out, int out_size, void* d_ws, size_t ws_size,
                              hipStream_t stream) {
    const float* pred = (const float*)d_in[0];
    const int* target = (const int*)d_in[1];
    float* out = (float*)d_out;
    float* ws_f = (float*)d_ws;

    int n = in_sizes[1];
    if (n * 2 != in_sizes[0]) n = in_sizes[0] / 2;   // defensive fallback
    const int npairs = n / 2;

    loss_partial_kernel<<<GRID, BLOCK, 0, stream>>>(
        (const f32x4*)pred, (const i32x2*)target, ws_f, npairs);
    loss_final_kernel<<<1, BLOCK, 0, stream>>>(ws_f, out, GRID, 1.0f / (float)n);
}

// Round 9
// 215.870 us; speedup vs baseline: 1.0065x; 1.0065x over previous
//
#include <hip/hip_runtime.h>

#define BLOCK 256
#define GRID 2048
#define UNROLL 16

typedef float f32x4 __attribute__((ext_vector_type(4)));
typedef int   i32x2 __attribute__((ext_vector_type(2)));

// Block-contiguous stride-1 layout, nontemporal loads, unroll x16
// (48 outstanding vector loads per wave, under the vmcnt=63 cap).
// One float4 = probs of 2 consecutive rows; one int2 = their targets.
__global__ __launch_bounds__(BLOCK) void loss_partial_kernel(
    const f32x4* __restrict__ pred4,  // N/2 elements (2 rows per float4)
    const i32x2* __restrict__ tgt2,   // N/2 elements (2 targets per int2)
    float* __restrict__ partials,     // GRID
    int npairs)                       // N/2
{
    const int ppb  = (npairs + GRID - 1) / GRID;   // 4096 pairs per block
    const int base = blockIdx.x * ppb;
    const int end  = min(base + ppb, npairs);

    float acc = 0.0f;
    int k = base + threadIdx.x;

    for (; k + (UNROLL - 1) * BLOCK < end; k += UNROLL * BLOCK) {
        f32x4 p[UNROLL];
        i32x2 t[UNROLL];
#pragma unroll
        for (int u = 0; u < UNROLL; ++u) p[u] = __builtin_nontemporal_load(&pred4[k + u * BLOCK]);
#pragma unroll
        for (int u = 0; u < UNROLL; ++u) t[u] = __builtin_nontemporal_load(&tgt2[k + u * BLOCK]);
#pragma unroll
        for (int u = 0; u < UNROLL; ++u) {
            {
                bool z = (t[u][0] == 0);
                float a = z ? p[u][0] : p[u][1];
                float b = z ? p[u][1] : p[u][0];
                float d = 1.0f - a;
                acc += fmaf(d, d, b * b) + ((a < b) ? 2.0f : 0.0f);
            }
            {
                bool z = (t[u][1] == 0);
                float a = z ? p[u][2] : p[u][3];
                float b = z ? p[u][3] : p[u][2];
                float d = 1.0f - a;
                acc += fmaf(d, d, b * b) + ((a < b) ? 2.0f : 0.0f);
            }
        }
    }
    for (; k < end; k += BLOCK) {   // tail (not taken at N=16777216: 16 exact steps)
        f32x4 p = __builtin_nontemporal_load(&pred4[k]);
        i32x2 t = __builtin_nontemporal_load(&tgt2[k]);
        {
            bool z = (t[0] == 0);
            float a = z ? p[0] : p[1];
            float b = z ? p[1] : p[0];
            float d = 1.0f - a;
            acc += fmaf(d, d, b * b) + ((a < b) ? 2.0f : 0.0f);
        }
        {
            bool z = (t[1] == 0);
            float a = z ? p[2] : p[3];
            float b = z ? p[3] : p[2];
            float d = 1.0f - a;
            acc += fmaf(d, d, b * b) + ((a < b) ? 2.0f : 0.0f);
        }
    }

#pragma unroll
    for (int off = 32; off > 0; off >>= 1)
        acc += __shfl_down(acc, off, 64);

    __shared__ float wsum[BLOCK / 64];
    const int lane = threadIdx.x & 63;
    const int wid  = threadIdx.x >> 6;
    if (lane == 0) wsum[wid] = acc;
    __syncthreads();
    if (threadIdx.x == 0) {
        float s = 0.0f;
#pragma unroll
        for (int w = 0; w < BLOCK / 64; ++w) s += wsum[w];
        partials[blockIdx.x] = s;
    }
}

__global__ __launch_bounds__(BLOCK) void loss_final_kernel(
    const float* __restrict__ partials, float* __restrict__ out,
    int nparts, float inv_n)
{
    float acc = 0.0f;
    for (int i = threadIdx.x; i < nparts; i += BLOCK)
        acc += partials[i];
#pragma unroll
    for (int off = 32; off > 0; off >>= 1)
        acc += __shfl_down(acc, off, 64);

    __shared__ float wsum[BLOCK / 64];
    const int lane = threadIdx.x & 63;
    const int wid  = threadIdx.x >> 6;
    if (lane == 0) wsum[wid] = acc;
    __syncthreads();
    if (threadIdx.x == 0) {
        float s = 0.0f;
#pragma unroll
        for (int w = 0; w < BLOCK / 64; ++w) s += wsum[w];
        out[0] = s * inv_n;
    }
}

extern "C" void kernel_launch(void* const* d_in, const int* in_sizes, int n_in,
                              void* d_out, int out_size, void* d_ws, size_t ws_size,
                              hipStream_t stream) {
    const float* pred = (const float*)d_in[0];
    const int* target = (const int*)d_in[1];
    float* out = (float*)d_out;
    float* ws_f = (float*)d_ws;

    int n = in_sizes[1];
    if (n * 2 != in_sizes[0]) n = in_sizes[0] / 2;   // defensive fallback
    const int npairs = n / 2;

    loss_partial_kernel<<<GRID, BLOCK, 0, stream>>>(
        (const f32x4*)pred, (const i32x2*)target, ws_f, npairs);
    loss_final_kernel<<<1, BLOCK, 0, stream>>>(ws_f, out, GRID, 1.0f / (float)n);
}